// Round 1
// 771.507 us; speedup vs baseline: 1.2490x; 1.2490x over previous
//
#include <hip/hip_runtime.h>
#include <hip/hip_fp16.h>

// Sinkhorn OT: n=m=4096, d=32, reg=0.1, 100 iterations, uniform marginals.
// R6 = R5 (fp16 K + K^T streaming rowpasses + exact-freeze) with the rowpass
// restructured for latency hiding:
//   - 2 waves per matrix row (8192 waves = 100% device wave capacity;
//     old: 1 wave/row = 4096 waves = 50% cap, observed 25% occupancy)
//   - 4 independent fdot2 accumulator chains per wave (old: one 32-deep
//     serial chain through a single acc)
//   - matrix loads issued BEFORE the LDS vector-staging write, so the
//     staging s_waitcnt + __syncthreads overlaps matrix-load latency
// Freeze logic unchanged: v16 bitwise 2-periodicity (detected at odd t via
// 8KB hist buffer) makes all remaining iterations bit-identical; sticky conv
// flag skips them. ws re-poison 0xAA is a safe hist init (sign bit set).

#define NN 4096
#define MM 4096
#define DD 32
#define N_ITERS 100

static constexpr float INV_REG = 10.0f;
static constexpr float A_MARG  = 1.0f / 4096.0f;
static constexpr float B_MARG  = 1.0f / 4096.0f;

typedef _Float16 h2_t __attribute__((ext_vector_type(2)));

static __device__ __forceinline__ float dot2(unsigned a, unsigned b, float acc) {
#if __has_builtin(__builtin_amdgcn_fdot2)
    return __builtin_amdgcn_fdot2(__builtin_bit_cast(h2_t, a),
                                  __builtin_bit_cast(h2_t, b), acc, false);
#else
    float2 fa = __half22float2(*(const __half2*)&a);
    float2 fb = __half22float2(*(const __half2*)&b);
    acc = fmaf(fa.x, fb.x, acc);
    return fmaf(fa.y, fb.y, acc);
#endif
}

static __device__ __forceinline__ unsigned ld_dev_u32(const unsigned* p) {
    return __hip_atomic_load(p, __ATOMIC_RELAXED, __HIP_MEMORY_SCOPE_AGENT);
}
static __device__ __forceinline__ void st_dev_u32(unsigned* p, unsigned v) {
    __hip_atomic_store(p, v, __ATOMIC_RELAXED, __HIP_MEMORY_SCOPE_AGENT);
}
static __device__ __forceinline__ unsigned short ld_dev_u16(const unsigned short* p) {
    return __hip_atomic_load(p, __ATOMIC_RELAXED, __HIP_MEMORY_SCOPE_AGENT);
}
static __device__ __forceinline__ void st_dev_u16(unsigned short* p, unsigned short v) {
    __hip_atomic_store(p, v, __ATOMIC_RELAXED, __HIP_MEMORY_SCOPE_AGENT);
}

// ---------------------------------------------------------------------------
// Kh[i][j] = (half)exp(-||p_i - q_j||^2 / reg). prime!=0: v16=1/4096,
// conv=0, slot=1 (slot must start nonzero; 0 means "no change observed").
// grid: (4096/256, 4096/16), block 256
// ---------------------------------------------------------------------------
__global__ void compute_K_half(const float* __restrict__ p, const float* __restrict__ q,
                               __half* __restrict__ Kh, __half* __restrict__ v16,
                               unsigned* __restrict__ conv, unsigned* __restrict__ slot,
                               int prime) {
    const int tid = threadIdx.x;
    const int j   = blockIdx.x * 256 + tid;
    const int r0  = blockIdx.y * 16;

    if (prime && blockIdx.y == 0) {
        v16[j] = __float2half(B_MARG);
        if (blockIdx.x == 0 && tid == 0) { *conv = 0u; *slot = 1u; }
    }

    float qv[DD];
    const float4* q4 = (const float4*)(q + (size_t)j * DD);
#pragma unroll
    for (int k = 0; k < DD / 4; ++k) {
        float4 t = q4[k];
        qv[4 * k + 0] = t.x; qv[4 * k + 1] = t.y;
        qv[4 * k + 2] = t.z; qv[4 * k + 3] = t.w;
    }

    __shared__ float ps[16 * DD];
    ps[tid]       = p[(size_t)r0 * DD + tid];
    ps[tid + 256] = p[(size_t)r0 * DD + tid + 256];
    __syncthreads();

#pragma unroll 4
    for (int ii = 0; ii < 16; ++ii) {
        float acc = 0.0f;
#pragma unroll
        for (int k = 0; k < DD; ++k) {
            float d = ps[ii * DD + k] - qv[k];
            acc = fmaf(d, d, acc);
        }
        Kh[(size_t)(r0 + ii) * MM + j] = __float2half(__expf(-acc * INV_REG));
    }
}

// ---------------------------------------------------------------------------
// u-pass: u[i] = a / (Kh[i,:] . v16). 512 blocks x 1024 thr (16 waves),
// 2 waves per row (each wave does one 4KB half-row, 4 uint4 loads, 4
// independent fdot2 chains), LDS partial combine, tid<8 finalizes 8 rows.
// Even t: if slot==0 (odd-parity v was 2-periodic) -> sticky conv, skip.
// Odd t: zero slot for this iter's v-pass detection.
// ---------------------------------------------------------------------------
__global__ void __launch_bounds__(1024, 8)
rowpass_u(const __half* __restrict__ Mat, const __half* __restrict__ w16_in,
          float* __restrict__ w32_out, __half* __restrict__ w16_out,
          unsigned* __restrict__ conv, unsigned* __restrict__ slot, int t) {
    if (ld_dev_u32(conv)) return;
    if ((t & 1) == 0) {
        if (ld_dev_u32(slot) == 0u) {   // frozen: u,v buffers already final
            if (threadIdx.x == 0) st_dev_u32(conv, 1u);
            return;
        }
    } else {
        if (blockIdx.x == 0 && threadIdx.x == 0) st_dev_u32(slot, 0u);
    }

    __shared__ __align__(16) __half vlds[MM];
    __shared__ float part[16];
    const int tid  = threadIdx.x;
    const int lane = tid & 63;
    const int w    = tid >> 6;          // wave 0..15
    const int rib  = w >> 1;            // row-in-block 0..7
    const int hlf  = w & 1;             // which half-row
    const int i    = blockIdx.x * 8 + rib;
    const uint4* __restrict__ Mrow = (const uint4*)(Mat + (size_t)i * MM);
    const int g0 = hlf * 256 + lane;    // uint4 index into 512-uint4 row

    // stage-load first, then matrix loads, THEN the LDS write: the write's
    // wait covers only the stage load (vmcnt is FIFO), matrix stays in flight
    uint4 stg;
    if (tid < 512) stg = ((const uint4*)w16_in)[tid];
    const uint4 k0 = Mrow[g0];
    const uint4 k1 = Mrow[g0 + 64];
    const uint4 k2 = Mrow[g0 + 128];
    const uint4 k3 = Mrow[g0 + 192];
    if (tid < 512) ((uint4*)vlds)[tid] = stg;
    __syncthreads();

    const uint4* V = (const uint4*)vlds;
    const uint4 v0 = V[g0];
    const uint4 v1 = V[g0 + 64];
    const uint4 v2 = V[g0 + 128];
    const uint4 v3 = V[g0 + 192];

    float a0 = 0.f, a1 = 0.f, a2 = 0.f, a3 = 0.f;
    a0 = dot2(k0.x, v0.x, a0); a0 = dot2(k0.y, v0.y, a0);
    a0 = dot2(k0.z, v0.z, a0); a0 = dot2(k0.w, v0.w, a0);
    a1 = dot2(k1.x, v1.x, a1); a1 = dot2(k1.y, v1.y, a1);
    a1 = dot2(k1.z, v1.z, a1); a1 = dot2(k1.w, v1.w, a1);
    a2 = dot2(k2.x, v2.x, a2); a2 = dot2(k2.y, v2.y, a2);
    a2 = dot2(k2.z, v2.z, a2); a2 = dot2(k2.w, v2.w, a2);
    a3 = dot2(k3.x, v3.x, a3); a3 = dot2(k3.y, v3.y, a3);
    a3 = dot2(k3.z, v3.z, a3); a3 = dot2(k3.w, v3.w, a3);
    float acc = (a0 + a1) + (a2 + a3);

#pragma unroll
    for (int off = 32; off > 0; off >>= 1) acc += __shfl_down(acc, off, 64);
    if (lane == 0) part[w] = acc;
    __syncthreads();

    if (tid < 8) {
        const int row = blockIdx.x * 8 + tid;
        float r = A_MARG / (part[2 * tid] + part[2 * tid + 1]);
        w32_out[row] = r;
        w16_out[row] = __float2half(r);
    }
}

// ---------------------------------------------------------------------------
// v-pass: v[j] = b / (KTh[j,:] . u16). Same structure. Odd t: compare new
// fp16 bits against hist (v from t-2, same parity); mismatch -> slot=1.
// ---------------------------------------------------------------------------
__global__ void __launch_bounds__(1024, 8)
rowpass_v(const __half* __restrict__ Mat, const __half* __restrict__ w16_in,
          float* __restrict__ w32_out, __half* __restrict__ w16_out,
          unsigned short* __restrict__ hist,
          unsigned* __restrict__ conv, unsigned* __restrict__ slot, int t) {
    if (ld_dev_u32(conv)) return;

    __shared__ __align__(16) __half vlds[MM];
    __shared__ float part[16];
    const int tid  = threadIdx.x;
    const int lane = tid & 63;
    const int w    = tid >> 6;
    const int rib  = w >> 1;
    const int hlf  = w & 1;
    const int i    = blockIdx.x * 8 + rib;
    const uint4* __restrict__ Mrow = (const uint4*)(Mat + (size_t)i * MM);
    const int g0 = hlf * 256 + lane;

    uint4 stg;
    if (tid < 512) stg = ((const uint4*)w16_in)[tid];
    const uint4 k0 = Mrow[g0];
    const uint4 k1 = Mrow[g0 + 64];
    const uint4 k2 = Mrow[g0 + 128];
    const uint4 k3 = Mrow[g0 + 192];
    if (tid < 512) ((uint4*)vlds)[tid] = stg;
    __syncthreads();

    const uint4* V = (const uint4*)vlds;
    const uint4 v0 = V[g0];
    const uint4 v1 = V[g0 + 64];
    const uint4 v2 = V[g0 + 128];
    const uint4 v3 = V[g0 + 192];

    float a0 = 0.f, a1 = 0.f, a2 = 0.f, a3 = 0.f;
    a0 = dot2(k0.x, v0.x, a0); a0 = dot2(k0.y, v0.y, a0);
    a0 = dot2(k0.z, v0.z, a0); a0 = dot2(k0.w, v0.w, a0);
    a1 = dot2(k1.x, v1.x, a1); a1 = dot2(k1.y, v1.y, a1);
    a1 = dot2(k1.z, v1.z, a1); a1 = dot2(k1.w, v1.w, a1);
    a2 = dot2(k2.x, v2.x, a2); a2 = dot2(k2.y, v2.y, a2);
    a2 = dot2(k2.z, v2.z, a2); a2 = dot2(k2.w, v2.w, a2);
    a3 = dot2(k3.x, v3.x, a3); a3 = dot2(k3.y, v3.y, a3);
    a3 = dot2(k3.z, v3.z, a3); a3 = dot2(k3.w, v3.w, a3);
    float acc = (a0 + a1) + (a2 + a3);

#pragma unroll
    for (int off = 32; off > 0; off >>= 1) acc += __shfl_down(acc, off, 64);
    if (lane == 0) part[w] = acc;
    __syncthreads();

    if (tid < 8) {
        const int row = blockIdx.x * 8 + tid;
        float r = B_MARG / (part[2 * tid] + part[2 * tid + 1]);
        w32_out[row] = r;
        const __half h = __float2half(r);
        if (t & 1) {
            const unsigned short bits = __half_as_ushort(h);
            const unsigned short old2 = ld_dev_u16(hist + row);
            if (old2 != bits) st_dev_u32(slot, 1u);
            st_dev_u16(hist + row, bits);
        }
        w16_out[row] = h;
    }
}

// ---------------------------------------------------------------------------
// gamma[i][j] = u[i] * exp(-||x_i-y_j||^2/reg) * v[j]   (exact fp32 K)
// grid: (16, 256), block 256
// ---------------------------------------------------------------------------
__global__ void epilogue(const float* __restrict__ x, const float* __restrict__ y,
                         const float* __restrict__ u, const float* __restrict__ v,
                         float* __restrict__ out) {
    const int tid = threadIdx.x;
    const int j   = blockIdx.x * 256 + tid;
    const int r0  = blockIdx.y * 16;

    float yv[DD];
    const float4* y4 = (const float4*)(y + (size_t)j * DD);
#pragma unroll
    for (int k = 0; k < DD / 4; ++k) {
        float4 t = y4[k];
        yv[4 * k + 0] = t.x; yv[4 * k + 1] = t.y;
        yv[4 * k + 2] = t.z; yv[4 * k + 3] = t.w;
    }

    __shared__ float xs[16 * DD];
    __shared__ float u_lds[16];
    xs[tid]       = x[(size_t)r0 * DD + tid];
    xs[tid + 256] = x[(size_t)r0 * DD + tid + 256];
    if (tid < 16) u_lds[tid] = u[r0 + tid];
    __syncthreads();

    const float vj = v[j];
#pragma unroll 4
    for (int ii = 0; ii < 16; ++ii) {
        float acc = 0.0f;
#pragma unroll
        for (int k = 0; k < DD; ++k) {
            float d = xs[ii * DD + k] - yv[k];
            acc = fmaf(d, d, acc);
        }
        out[(size_t)(r0 + ii) * MM + j] = u_lds[ii] * __expf(-acc * INV_REG) * vj;
    }
}

extern "C" void kernel_launch(void* const* d_in, const int* in_sizes, int n_in,
                              void* d_out, int out_size, void* d_ws, size_t ws_size,
                              hipStream_t stream) {
    const float* x = (const float*)d_in[0];
    const float* y = (const float*)d_in[1];
    __half*   Kh   = (__half*)d_ws;                    // 32 MB
    __half*   KTh  = Kh + (size_t)NN * MM;             // 32 MB
    float*    u32  = (float*)(KTh + (size_t)NN * MM);  // 16 KB
    float*    v32  = u32 + NN;                         // 16 KB
    __half*   u16  = (__half*)(v32 + MM);              // 8 KB
    __half*   v16  = u16 + NN;                         // 8 KB
    unsigned short* hist = (unsigned short*)(v16 + MM);// 8 KB (0xAA-poison safe)
    unsigned* conv = (unsigned*)(hist + MM);           // 4 B
    unsigned* slot = conv + 1;                         // 4 B
    float*    out  = (float*)d_out;

    compute_K_half<<<dim3(MM / 256, NN / 16), 256, 0, stream>>>(x, y, Kh, v16, conv, slot, 1);
    compute_K_half<<<dim3(NN / 256, MM / 16), 256, 0, stream>>>(y, x, KTh, v16, conv, slot, 0);

    for (int t = 0; t < N_ITERS; ++t) {
        rowpass_u<<<NN / 8, 1024, 0, stream>>>(Kh,  v16, u32, u16, conv, slot, t);
        rowpass_v<<<MM / 8, 1024, 0, stream>>>(KTh, u16, v32, v16, hist, conv, slot, t);
    }

    epilogue<<<dim3(MM / 256, NN / 16), 256, 0, stream>>>(x, y, u32, v32, out);
}